// Round 7
// baseline (419.063 us; speedup 1.0000x reference)
//
#include <hip/hip_runtime.h>
#include <hip/hip_bf16.h>
#include <stdint.h>

#define NINF -100000.0f

constexpr int Bn = 64, Tn = 512, Hn = 768, Nn = 25;

typedef float float2v __attribute__((ext_vector_type(2)));

__device__ inline float2v pk_mul(float2v a, float2v b) {
    float2v d;
    asm("v_pk_mul_f32 %0, %1, %2" : "=v"(d) : "v"(a), "v"(b));
    return d;
}
__device__ inline float2v pk_add(float2v a, float2v b) {
    float2v d;
    asm("v_pk_add_f32 %0, %1, %2" : "=v"(d) : "v"(a), "v"(b));
    return d;
}

__device__ inline float ldf(const void* p, size_t i, bool isbf) {
    if (isbf) return __bfloat162float(((const __hip_bfloat16*)p)[i]);
    return ((const float*)p)[i];
}
__device__ inline int ldb(const void* p, int i, int bw) {
    if (bw == 1) return (int)((const uint8_t*)p)[i];
    if (bw == 8) return ((const int*)p)[2 * i];
    return ((const int*)p)[i];
}

__device__ inline float rdlane(float v, int lane) {
    return __int_as_float(__builtin_amdgcn_readlane(__float_as_int(v), lane));
}
__device__ inline int imin2(int a, int b) { return a < b ? a : b; }

// exact max of 25 (fmaxf tree — associative, no rounding; max3-friendly shape)
__device__ inline float amax25(const float* s) {
    float a0 = fmaxf(fmaxf(s[0],  s[1]),  s[2]);
    float a1 = fmaxf(fmaxf(s[3],  s[4]),  s[5]);
    float a2 = fmaxf(fmaxf(s[6],  s[7]),  s[8]);
    float a3 = fmaxf(fmaxf(s[9],  s[10]), s[11]);
    float a4 = fmaxf(fmaxf(s[12], s[13]), s[14]);
    float a5 = fmaxf(fmaxf(s[15], s[16]), s[17]);
    float a6 = fmaxf(fmaxf(s[18], s[19]), s[20]);
    float a7 = fmaxf(fmaxf(s[21], s[22]), s[23]);
    float b0 = fmaxf(fmaxf(a0, a1), a2);
    float b1 = fmaxf(fmaxf(a3, a4), a5);
    float b2 = fmaxf(fmaxf(a6, a7), s[24]);
    return fmaxf(fmaxf(b0, b1), b2);
}

// one steady-state (t < last) recurrence step: pure VALU, no LDS
__device__ inline float stepx(float areg, float Lg, const float* ttc) {
    float s[25];
    {
#pragma clang fp contract(off)
#pragma unroll
        for (int k = 0; k < 25; k++) {
            float ak = rdlane(areg, k);    // SGPR broadcast of alpha[k]
            s[k] = ak + (Lg + ttc[k]);
        }
    }
    return amax25(s);
}

// ---------------- front: gemm (blocks 0..511) + prep (blocks 512..575) -----------
// gemm blocks convert W/b inline from the raw tensors (coalesced reads, local dtype
// detect) — no dependency on the prep blocks, so the whole front is one dispatch.
// Per-j accumulation is sequential f32 (separate mul then add via v_pk_*, NO fma)
// over h = 0..767 ascending — bit-identical to the reference C-einsum loop.
__global__ __launch_bounds__(128) void k_front(
    const void* embv, const void* mask, const void* padidx,
    const void* W, const void* bv, const void* trans, const void* startt, const void* endt,
    const void* sc, const void* ec, const void* tc,
    int* flags, float* wstrans, float* wstc,
    float* wsstart, float* wsend, float* wsscm, float* wsecm,
    int* lengths, float* logitsF)
{
    __shared__ float etile[64][76];    // rows 304 B (16B-aligned); stride 19 banks (odd)
    __shared__ float wtile[64][32];    // 64-h chunk x 25 cols (reads are broadcasts)
    __shared__ float s_b[25];
    __shared__ int   s_isbf;
    __shared__ int   ws2[2];

    int tid = threadIdx.x;
    int bid = blockIdx.x;

    // local dtype detect (wave 0; deterministic, same answer in every block)
    if (tid < 64) {
        const uint16_t* e16 = (const uint16_t*)embv;
        uint16_t v = e16[tid];
        int ex = (v >> 7) & 0xFF;
        bool sane = (ex >= 100 && ex <= 140);
        unsigned long long ball = __ballot(sane);
        if (tid == 0) s_isbf = (__popcll(ball) >= 56) ? 1 : 0;
    }
    __syncthreads();
    bool isbf = s_isbf != 0;

    if (bid >= 512) {
        // ---------------- prep ----------------
        int pb = bid - 512;              // 0..63
        const int* mw = (const int*)mask;
        int w0 = mw[0], w1 = mw[1];
        int bw;
        if ((unsigned)w0 > 1u) bw = 1;
        else if (w0 == 1 && w1 == 0) bw = 8;
        else bw = 4;
        if (pb == 0 && tid == 0) {
            flags[0] = isbf ? 1 : 0;
            flags[1] = bw;
            flags[2] = ((const int*)padidx)[0];
        }
        // lengths[pb]
        {
            int s = 0;
#pragma unroll
            for (int u = 0; u < 4; u++)
                s += (ldb(mask, pb * Tn + u * 128 + tid, bw) ? 1 : 0);
            for (int off = 32; off; off >>= 1) s += __shfl_down(s, off, 64);
            if ((tid & 63) == 0) ws2[tid >> 6] = s;
            __syncthreads();
            if (tid == 0) lengths[pb] = ws2[0] + ws2[1];
        }
        // conversions, grid-strided over the 64 prep blocks
        int gid = pb * 128 + tid;
        int gsz = 64 * 128;
        for (int i = gid; i < Nn; i += gsz) {
            wsstart[i] = ldf(startt, i, isbf);
            wsend[i]   = ldf(endt, i, isbf);
            wsscm[i]   = ldb(sc, i, bw) ? 0.0f : NINF;
            wsecm[i]   = ldb(ec, i, bw) ? 0.0f : NINF;
        }
        for (int i = gid; i < Nn * Nn; i += gsz) {
            wstrans[i] = ldf(trans, i, isbf);
            wstc[i]    = ldb(tc, i, bw) ? 0.0f : NINF;
        }
        return;
    }

    // ---------------- gemm ----------------
    int r    = tid >> 1;               // row within block: 0..63
    int half = tid & 1;
    int j0   = half ? 12 : 0;          // half0: j 0..11, half1: j 12..24
    int row0 = bid * 64;
    int row  = row0 + r;

    if (tid < 25) s_b[tid] = ldf(bv, tid, isbf);

    float2v acc2[6];
#pragma unroll
    for (int k = 0; k < 6; k++) acc2[k] = (float2v){0.0f, 0.0f};
    float acc12 = 0.0f;                // half1: j24; half0: dummy (j12, unused)

    for (int c = 0; c < 12; c++) {
        __syncthreads();
        // stage 64 rows x 64 h — vectorized global loads, single b128 LDS write
        if (isbf) {
            const uint16_t* ep = (const uint16_t*)embv;
#pragma unroll
            for (int it = 0; it < 8; it++) {
                int idx = it * 128 + tid;        // 0..1023
                int rr = idx >> 4;
                int q  = idx & 15;
                const ushort4* p4 = (const ushort4*)(ep + (size_t)(row0 + rr) * Hn + c * 64);
                ushort4 u = p4[q];
                float4 f;
                f.x = __bfloat162float(*(const __hip_bfloat16*)&u.x);
                f.y = __bfloat162float(*(const __hip_bfloat16*)&u.y);
                f.z = __bfloat162float(*(const __hip_bfloat16*)&u.z);
                f.w = __bfloat162float(*(const __hip_bfloat16*)&u.w);
                *(float4*)&etile[rr][q * 4] = f;
            }
        } else {
            const float* ep = (const float*)embv;
#pragma unroll
            for (int it = 0; it < 8; it++) {
                int idx = it * 128 + tid;
                int rr = idx >> 4;
                int q  = idx & 15;
                const float4* p4 = (const float4*)(ep + (size_t)(row0 + rr) * Hn + c * 64);
                *(float4*)&etile[rr][q * 4] = p4[q];
            }
        }
        // stage W chunk directly from raw input (contiguous = coalesced)
        for (int i = tid; i < 1600; i += 128) {
            int hh = i / 25, jj = i - hh * 25;
            wtile[hh][jj] = ldf(W, (size_t)c * 1600 + i, isbf);
        }
        __syncthreads();
        {
#pragma clang fp contract(off)
            for (int h4 = 0; h4 < 16; h4++) {
                float4 e4 = *(const float4*)&etile[r][h4 * 4];
#pragma unroll
                for (int u = 0; u < 4; u++) {
                    int hh = h4 * 4 + u;
                    float e = (u == 0) ? e4.x : (u == 1) ? e4.y : (u == 2) ? e4.z : e4.w;
                    float2v ee = (float2v){e, e};
                    const float4* wp = (const float4*)&wtile[hh][j0];
                    float4 w0 = wp[0];
                    float4 w1 = wp[1];
                    float4 w2 = wp[2];
                    float  wl = wtile[hh][j0 + 12];
                    acc2[0] = pk_add(acc2[0], pk_mul(ee, (float2v){w0.x, w0.y}));
                    acc2[1] = pk_add(acc2[1], pk_mul(ee, (float2v){w0.z, w0.w}));
                    acc2[2] = pk_add(acc2[2], pk_mul(ee, (float2v){w1.x, w1.y}));
                    acc2[3] = pk_add(acc2[3], pk_mul(ee, (float2v){w1.z, w1.w}));
                    acc2[4] = pk_add(acc2[4], pk_mul(ee, (float2v){w2.x, w2.y}));
                    acc2[5] = pk_add(acc2[5], pk_mul(ee, (float2v){w2.z, w2.w}));
                    acc12 = acc12 + e * wl;
                }
            }
        }
    }

    // logits = einsum + b  (one f32 add, ref association); halves write disjoint j
    {
#pragma clang fp contract(off)
#pragma unroll
        for (int p = 0; p < 6; p++) {
            int j = j0 + 2 * p;
            logitsF[(size_t)row * 25 + j]     = acc2[p][0] + s_b[j];
            logitsF[(size_t)row * 25 + j + 1] = acc2[p][1] + s_b[j + 1];
        }
        if (half) logitsF[(size_t)row * 25 + 24] = acc12 + s_b[24];
    }
}

// ---------------- tail: viterbi (blocks 0..63) + lp (blocks 64..2111), fused ------
// Phase A (wave 0): max-only recurrence, 8-step unrolled body — 8 Lg LDS reads
// batched up front (one waitcnt per 8 steps), 8 pure-VALU steps, 8 alpha stores
// batched after. Scalar remainder + exact t==last epilogue.
// Phase B (8 waves): recompute s[k] bit-identically from stored alpha rows,
// equality-scan vs the stored row max, min-tree -> bp[t][j].
// Trace (wave 0): readlane-chain backtrack.
struct SharedV {
    float   lgl[Tn * Nn];    // 51200 B
    float   alpha[Tn][26];   // 53248 B
    uint8_t bp[511][32];     // 16352 B
    uint8_t tags[512];
};
struct SharedL {
    float s_trans[625];
    float s_start[25];
    float s_end[25];
};

__global__ __launch_bounds__(512) void k_tail(
    const float* logitsF, const float* wstrans, const float* wstc,
    const float* wsstart, const float* wsend, const float* wsscm, const float* wsecm,
    const int* lengths, const int* flags, void* out)
{
    __shared__ union { SharedV v; SharedL l; } smem;
    int tid = threadIdx.x;
    bool isbf = flags[0] != 0;

    if (blockIdx.x >= 64) {
        // ---------------- lp expansion ----------------
        for (int i = tid; i < 625; i += 512) smem.l.s_trans[i] = wstrans[i];
        if (tid < 25) { smem.l.s_start[tid] = wsstart[tid]; smem.l.s_end[tid] = wsend[tid]; }
        __syncthreads();

        int rw0 = (blockIdx.x - 64) * 16;    // 16 (b,t) rows, same batch
        int b = rw0 >> 9;
        int last = lengths[b] - 1;
        const float* lg0 = logitsF + (size_t)rw0 * 25;
        size_t obase = (size_t)rw0 * 625;

        for (int idx = tid; idx < 16 * 625; idx += 512) {
            int rr = idx / 625;
            int e  = idx - rr * 625;
            int j  = e % 25;
            int t  = (rw0 + rr) & 511;
            float lg = lg0[rr * 25 + j];
            float v;
            {
#pragma clang fp contract(off)
                if (t == 0) v = smem.l.s_start[j] + lg;
                else        v = lg + smem.l.s_trans[e];
                if (t == last) v += smem.l.s_end[j];
            }
            size_t o = obase + idx;
            if (isbf) ((__hip_bfloat16*)out)[o] = __float2bfloat16(v);
            else      ((float*)out)[o] = v;
        }
        return;
    }

    // ---------------- viterbi ----------------
    int b  = blockIdx.x;
    int len  = lengths[b];
    int last = len - 1;
    int padv = flags[2];
    int L   = tid & 63;
    int wid = tid >> 6;
    bool act = (L < 25);
    int j = act ? L : 0;

    // stage this batch's logits into LDS (coalesced float4, all 8 waves)
    {
        const float4* src = (const float4*)(logitsF + (size_t)b * (Tn * Nn));
        float4* dst = (float4*)smem.v.lgl;
        for (int i = tid; i < (Tn * Nn) / 4; i += 512) dst[i] = src[i];
    }

    // loop-invariant per-lane columns — loaded by ALL waves (phase B needs them).
    float tcol[25], tccol[25], ttc[25];
#pragma unroll
    for (int k = 0; k < 25; k++) {
        tcol[k]  = wstrans[k * 25 + j];
        tccol[k] = wstc[k * 25 + j];
        // ttc pre-add exact when tc==0 (only candidates that can win a followed
        // argmax; tc|eye guarantees the self-loop so NINF-class candidates lose
        // by >=9e4 — reassociation unobservable).
        ttc[k] = tcol[k] + tccol[k];
    }
    float endj = wsend[j];
    float ecmj = wsecm[j];

    __syncthreads();   // lgl ready

    float areg = 0.0f;   // final alpha (valid in wave 0 lanes 0..24 after phase A)
    if (wid == 0) {
        // ---- phase A: max-only forward, 8-step unrolled, batched LDS ----
        {
#pragma clang fp contract(off)
            areg = (wsstart[j] + smem.v.lgl[j]) + wsscm[j];
        }
        if (act) smem.v.alpha[0][L] = areg;

        int tEndX = last - 1;            // inclusive end of steady-state steps
        int t = 1;
        for (; t + 7 <= tEndX; t += 8) {
            float Lg8[8];
#pragma unroll
            for (int u = 0; u < 8; u++) Lg8[u] = smem.v.lgl[(t + u) * 25 + j];
            float a8[8];
#pragma unroll
            for (int u = 0; u < 8; u++) { areg = stepx(areg, Lg8[u], ttc); a8[u] = areg; }
            if (act) {
#pragma unroll
                for (int u = 0; u < 8; u++) smem.v.alpha[t + u][L] = a8[u];
            }
        }
        for (; t <= tEndX; ++t) {
            float Lg = smem.v.lgl[t * 25 + j];
            areg = stepx(areg, Lg, ttc);
            if (act) smem.v.alpha[t][L] = areg;
        }
        // final step t = last (end-transition formula, exact R6 ordering)
        {
            float Lg = smem.v.lgl[last * 25 + j];
            float s[25];
            {
#pragma clang fp contract(off)
#pragma unroll
                for (int k = 0; k < 25; k++) {
                    float ak = rdlane(areg, k);
                    float v = (((Lg + tcol[k]) + endj) + tccol[k]) + ecmj;
                    s[k] = ak + v;
                }
            }
            areg = amax25(s);
            if (act) smem.v.alpha[last][L] = areg;
        }
    }
    __syncthreads();   // alpha rows ready

    // ---- phase B: bp[t][j], 8-way parallel over t ----
    for (int t = 1 + wid; t <= last; t += 8) {
        float ap = smem.v.alpha[t - 1][j];   // lane L holds alpha[t-1][L]
        float mj = smem.v.alpha[t][j];       // this j's row max
        float Lg = smem.v.lgl[t * 25 + j];

        float s[25];
        if (t < last) {
#pragma clang fp contract(off)
#pragma unroll
            for (int k = 0; k < 25; k++) {
                float ak = rdlane(ap, k);
                s[k] = ak + (Lg + ttc[k]);
            }
        } else {
#pragma clang fp contract(off)
#pragma unroll
            for (int k = 0; k < 25; k++) {
                float ak = rdlane(ap, k);
                float v = (((Lg + tcol[k]) + endj) + tccol[k]) + ecmj;
                s[k] = ak + v;
            }
        }

        // first index with s[k]==mj  (== jnp.argmax first-occurrence; s recomputed
        // bit-identically to phase A, and the fmax-tree max is exact)
        int ik[25];
#pragma unroll
        for (int k = 0; k < 25; k++) ik[k] = (s[k] == mj) ? k : 32;
        int q0 = imin2(imin2(ik[0],  ik[1]),  ik[2]);
        int q1 = imin2(imin2(ik[3],  ik[4]),  ik[5]);
        int q2 = imin2(imin2(ik[6],  ik[7]),  ik[8]);
        int q3 = imin2(imin2(ik[9],  ik[10]), ik[11]);
        int q4 = imin2(imin2(ik[12], ik[13]), ik[14]);
        int q5 = imin2(imin2(ik[15], ik[16]), ik[17]);
        int q6 = imin2(imin2(ik[18], ik[19]), ik[20]);
        int q7 = imin2(imin2(ik[21], ik[22]), ik[23]);
        int r0 = imin2(imin2(q0, q1), q2);
        int r1 = imin2(imin2(q3, q4), q5);
        int r2 = imin2(imin2(q6, q7), ik[24]);
        int mi = imin2(imin2(r0, r1), r2);

        if (act) smem.v.bp[t - 1][L] = (uint8_t)mi;
    }
    __syncthreads();   // bp ready

    if (wid == 0) {
        // wave-uniform argmax over final alpha (readlane chain, first-max)
        float am = rdlane(areg, 0);
        int ami = 0;
#pragma unroll
        for (int k = 1; k < 25; k++) {
            float v2 = rdlane(areg, k);
            bool g = v2 > am;
            am  = g ? v2 : am;
            ami = g ? k  : ami;
        }
        int tag = ami;
        if (L == 0) smem.v.tags[last] = (uint8_t)tag;

        // backtrack: prefetch 8 bp rows per chunk (independent LDS reads), then
        // chain only through dynamic-lane readlane.
        int Lc = L & 31;
        int k2 = last - 1;
        while (k2 >= 7) {
            int c0 = smem.v.bp[k2    ][Lc];
            int c1 = smem.v.bp[k2 - 1][Lc];
            int c2 = smem.v.bp[k2 - 2][Lc];
            int c3 = smem.v.bp[k2 - 3][Lc];
            int c4 = smem.v.bp[k2 - 4][Lc];
            int c5 = smem.v.bp[k2 - 5][Lc];
            int c6 = smem.v.bp[k2 - 6][Lc];
            int c7 = smem.v.bp[k2 - 7][Lc];
            tag = __builtin_amdgcn_readlane(c0, tag); if (L == 0) smem.v.tags[k2    ] = (uint8_t)tag;
            tag = __builtin_amdgcn_readlane(c1, tag); if (L == 0) smem.v.tags[k2 - 1] = (uint8_t)tag;
            tag = __builtin_amdgcn_readlane(c2, tag); if (L == 0) smem.v.tags[k2 - 2] = (uint8_t)tag;
            tag = __builtin_amdgcn_readlane(c3, tag); if (L == 0) smem.v.tags[k2 - 3] = (uint8_t)tag;
            tag = __builtin_amdgcn_readlane(c4, tag); if (L == 0) smem.v.tags[k2 - 4] = (uint8_t)tag;
            tag = __builtin_amdgcn_readlane(c5, tag); if (L == 0) smem.v.tags[k2 - 5] = (uint8_t)tag;
            tag = __builtin_amdgcn_readlane(c6, tag); if (L == 0) smem.v.tags[k2 - 6] = (uint8_t)tag;
            tag = __builtin_amdgcn_readlane(c7, tag); if (L == 0) smem.v.tags[k2 - 7] = (uint8_t)tag;
            k2 -= 8;
        }
        while (k2 >= 0) {
            int c = smem.v.bp[k2][Lc];
            tag = __builtin_amdgcn_readlane(c, tag);
            if (L == 0) smem.v.tags[k2] = (uint8_t)tag;
            k2--;
        }
    }
    __syncthreads();

    size_t base = 20480000ull;  // B*T*N*N
    {
        int t = tid;            // 512 threads, one element each
        float val = (t < len) ? (float)smem.v.tags[t] : (float)padv;
        size_t o = base + (size_t)b * 512 + t;
        if (isbf) ((__hip_bfloat16*)out)[o] = __float2bfloat16(val);
        else      ((float*)out)[o] = val;
    }
}

extern "C" void kernel_launch(void* const* d_in, const int* in_sizes, int n_in,
                              void* d_out, int out_size, void* d_ws, size_t ws_size,
                              hipStream_t stream) {
    const void* emb  = d_in[0];
    const void* W    = d_in[1];
    const void* bv   = d_in[2];
    const void* tr   = d_in[3];
    const void* st   = d_in[4];
    const void* en   = d_in[5];
    const void* mask = d_in[6];
    const void* sc   = d_in[7];
    const void* ec   = d_in[8];
    const void* tc   = d_in[9];
    const void* pad  = d_in[10];

    char* ws = (char*)d_ws;
    int*    flags    = (int*)ws;             // 64 B
    int*    lengths  = (int*)(ws + 64);      // 256 B
    float*  wsstart  = (float*)(ws + 512);
    float*  wsend    = (float*)(ws + 640);
    float*  wsscm    = (float*)(ws + 768);
    float*  wsecm    = (float*)(ws + 896);
    float*  wstrans  = (float*)(ws + 1024);  // 2500 B
    float*  wstc     = (float*)(ws + 3584);  // 2500 B
    float*  logitsF  = (float*)(ws + 82944); // 3276800 B -> ends ~3.36 MB

    k_front<<<576, 128, 0, stream>>>(emb, mask, pad, W, bv, tr, st, en, sc, ec, tc,
                                     flags, wstrans, wstc, wsstart, wsend, wsscm, wsecm,
                                     lengths, logitsF);
    k_tail<<<2112, 512, 0, stream>>>(logitsF, wstrans, wstc, wsstart, wsend,
                                     wsscm, wsecm, lengths, flags, d_out);
}

// Round 8
// 373.205 us; speedup vs baseline: 1.1229x; 1.1229x over previous
//
#include <hip/hip_runtime.h>
#include <hip/hip_bf16.h>
#include <stdint.h>

#define NINF -100000.0f

constexpr int Bn = 64, Tn = 512, Hn = 768, Nn = 25;

typedef float float2v __attribute__((ext_vector_type(2)));
typedef unsigned short ushortv8 __attribute__((ext_vector_type(8)));

__device__ inline float2v pk_mul(float2v a, float2v b) {
    float2v d;
    asm("v_pk_mul_f32 %0, %1, %2" : "=v"(d) : "v"(a), "v"(b));
    return d;
}
__device__ inline float2v pk_add(float2v a, float2v b) {
    float2v d;
    asm("v_pk_add_f32 %0, %1, %2" : "=v"(d) : "v"(a), "v"(b));
    return d;
}

__device__ inline float ldf(const void* p, size_t i, bool isbf) {
    if (isbf) return __bfloat162float(((const __hip_bfloat16*)p)[i]);
    return ((const float*)p)[i];
}
__device__ inline int ldb(const void* p, int i, int bw) {
    if (bw == 1) return (int)((const uint8_t*)p)[i];
    if (bw == 8) return ((const int*)p)[2 * i];
    return ((const int*)p)[i];
}
__device__ inline float bf2f(uint16_t h) {
    return __bfloat162float(*(const __hip_bfloat16*)&h);
}

__device__ inline float rdlane(float v, int lane) {
    return __int_as_float(__builtin_amdgcn_readlane(__float_as_int(v), lane));
}
__device__ inline int imin2(int a, int b) { return a < b ? a : b; }

// exact max of 25 (fmaxf tree — associative, no rounding; max3-friendly shape)
__device__ inline float amax25(const float* s) {
    float a0 = fmaxf(fmaxf(s[0],  s[1]),  s[2]);
    float a1 = fmaxf(fmaxf(s[3],  s[4]),  s[5]);
    float a2 = fmaxf(fmaxf(s[6],  s[7]),  s[8]);
    float a3 = fmaxf(fmaxf(s[9],  s[10]), s[11]);
    float a4 = fmaxf(fmaxf(s[12], s[13]), s[14]);
    float a5 = fmaxf(fmaxf(s[15], s[16]), s[17]);
    float a6 = fmaxf(fmaxf(s[18], s[19]), s[20]);
    float a7 = fmaxf(fmaxf(s[21], s[22]), s[23]);
    float b0 = fmaxf(fmaxf(a0, a1), a2);
    float b1 = fmaxf(fmaxf(a3, a4), a5);
    float b2 = fmaxf(fmaxf(a6, a7), s[24]);
    return fmaxf(fmaxf(b0, b1), b2);
}

// one steady-state (t < last) recurrence step: pure VALU, no LDS
__device__ inline float stepx(float areg, float Lg, const float* ttc) {
    float s[25];
    {
#pragma clang fp contract(off)
#pragma unroll
        for (int k = 0; k < 25; k++) {
            float ak = rdlane(areg, k);    // SGPR broadcast of alpha[k]
            s[k] = ak + (Lg + ttc[k]);
        }
    }
    return amax25(s);
}

// ---------------- prep: detect + convert (small) + lengths ----------------
__global__ __launch_bounds__(256) void k_prep(
    const void* emb, const void* mask, const void* padidx,
    const void* trans, const void* startt, const void* endt,
    const void* sc, const void* ec, const void* tc,
    int* flags, float* wsstart, float* wsend, float* wsscm, float* wsecm,
    float* wstrans, float* wstc, int* lengths)
{
    __shared__ int s_isbf, s_bw;
    __shared__ int ws4[4];
    int blk = blockIdx.x;
    int tid = threadIdx.x;

    if (tid < 64) {
        const uint16_t* e16 = (const uint16_t*)emb;
        uint16_t v = e16[tid];
        int ex = (v >> 7) & 0xFF;
        bool sane = (ex >= 100 && ex <= 140);
        unsigned long long ball = __ballot(sane);
        int cnt = __popcll(ball);
        if (tid == 0) {
            int isbf = (cnt >= 56) ? 1 : 0;
            const int* mw = (const int*)mask;
            int w0 = mw[0];
            int w1 = mw[1];
            int bw;
            if ((unsigned)w0 > 1u) bw = 1;
            else if (w0 == 1 && w1 == 0) bw = 8;
            else bw = 4;
            s_isbf = isbf; s_bw = bw;
            if (blk == 0) {
                flags[0] = isbf;
                flags[1] = bw;
                flags[2] = ((const int*)padidx)[0];
            }
        }
    }
    __syncthreads();
    bool isbf = s_isbf != 0;
    int bw = s_bw;

    {
        int s = (ldb(mask, blk * Tn + tid, bw) ? 1 : 0)
              + (ldb(mask, blk * Tn + 256 + tid, bw) ? 1 : 0);
        for (int off = 32; off; off >>= 1) s += __shfl_down(s, off, 64);
        if ((tid & 63) == 0) ws4[tid >> 6] = s;
        __syncthreads();
        if (tid == 0) lengths[blk] = ws4[0] + ws4[1] + ws4[2] + ws4[3];
    }

    int gid = blk * 256 + tid;
    int gsz = 64 * 256;
    for (int i = gid; i < Nn; i += gsz) {
        wsstart[i] = ldf(startt, i, isbf);
        wsend[i]   = ldf(endt, i, isbf);
        wsscm[i]   = ldb(sc, i, bw) ? 0.0f : NINF;
        wsecm[i]   = ldb(ec, i, bw) ? 0.0f : NINF;
    }
    for (int i = gid; i < Nn * Nn; i += gsz) {
        wstrans[i] = ldf(trans, i, isbf);
        wstc[i]    = ldb(tc, i, bw) ? 0.0f : NINF;
    }
}

// ---------------- logits: barrier-free K loop, whole W in LDS ----------------
// 256 blocks x 256 threads, 128 rows/block, 2 threads/row (j 0..11 | 12..24).
// All of W (768x25 f32, stride-28-padded for 16B-aligned broadcast float4 reads)
// is staged ONCE per block; the 12-chunk K loop has NO barriers — each thread
// streams its own row's emb directly to registers (16B loads, double-buffered).
// Per-j accumulation is sequential f32 (separate mul then add via v_pk_*, NO fma)
// over h = 0..767 ascending — bit-identical to the reference C-einsum loop.
__global__ __launch_bounds__(256) void k_gemm(
    const void* embv, const void* W, const void* bv, float* logitsF)
{
    __shared__ float wall[768 * 28];   // 86016 B
    __shared__ float s_b[25];
    __shared__ int   s_isbf;

    int tid = threadIdx.x;

    // local dtype detect (wave 0; deterministic, same answer in every block)
    if (tid < 64) {
        const uint16_t* e16 = (const uint16_t*)embv;
        uint16_t v = e16[tid];
        int ex = (v >> 7) & 0xFF;
        bool sane = (ex >= 100 && ex <= 140);
        unsigned long long ball = __ballot(sane);
        if (tid == 0) s_isbf = (__popcll(ball) >= 56) ? 1 : 0;
    }
    __syncthreads();
    bool isbf = s_isbf != 0;

    // stage ALL of W into LDS (one-time, vectorized)
    if (isbf) {
        const ushortv8* wp = (const ushortv8*)W;
        for (int k = tid; k < 2400; k += 256) {      // 2400*8 = 19200 elems
            ushortv8 u = wp[k];
            int base = k * 8;
#pragma unroll
            for (int uu = 0; uu < 8; uu++) {
                int e = base + uu;
                int hh = e / 25, jj = e - hh * 25;
                wall[hh * 28 + jj] = bf2f(u[uu]);
            }
        }
    } else {
        const float4* wp = (const float4*)W;
        for (int k = tid; k < 4800; k += 256) {      // 4800*4 = 19200 elems
            float4 f = wp[k];
            int base = k * 4;
#pragma unroll
            for (int uu = 0; uu < 4; uu++) {
                int e = base + uu;
                int hh = e / 25, jj = e - hh * 25;
                float v = (uu == 0) ? f.x : (uu == 1) ? f.y : (uu == 2) ? f.z : f.w;
                wall[hh * 28 + jj] = v;
            }
        }
    }
    if (tid < 25) s_b[tid] = ldf(bv, tid, isbf);
    __syncthreads();   // wall + s_b ready; no more barriers

    int r    = tid >> 1;
    int half = tid & 1;
    int j0   = half ? 12 : 0;
    int row  = blockIdx.x * 128 + r;

    float2v acc2[6];
#pragma unroll
    for (int k = 0; k < 6; k++) acc2[k] = (float2v){0.0f, 0.0f};
    float acc12 = 0.0f;                // half1: j24; half0: dummy (j12, unused)

    if (isbf) {
        const ushortv8* ep = (const ushortv8*)((const uint16_t*)embv + (size_t)row * Hn);
        ushortv8 eA[8], eB[8];
#pragma unroll
        for (int g = 0; g < 8; g++) eA[g] = ep[g];
        for (int c = 0; c < 12; c++) {
            if (c < 11) {
#pragma unroll
                for (int g = 0; g < 8; g++) eB[g] = ep[(c + 1) * 8 + g];
            }
            {
#pragma clang fp contract(off)
#pragma unroll
                for (int g = 0; g < 8; g++) {
#pragma unroll
                    for (int u = 0; u < 8; u++) {
                        int hg = c * 64 + g * 8 + u;
                        float e = bf2f(eA[g][u]);
                        float2v ee = (float2v){e, e};
                        const float4* wp4 = (const float4*)&wall[hg * 28 + j0];
                        float4 w0 = wp4[0];
                        float4 w1 = wp4[1];
                        float4 w2 = wp4[2];
                        float  wl = wall[hg * 28 + j0 + 12];
                        acc2[0] = pk_add(acc2[0], pk_mul(ee, (float2v){w0.x, w0.y}));
                        acc2[1] = pk_add(acc2[1], pk_mul(ee, (float2v){w0.z, w0.w}));
                        acc2[2] = pk_add(acc2[2], pk_mul(ee, (float2v){w1.x, w1.y}));
                        acc2[3] = pk_add(acc2[3], pk_mul(ee, (float2v){w1.z, w1.w}));
                        acc2[4] = pk_add(acc2[4], pk_mul(ee, (float2v){w2.x, w2.y}));
                        acc2[5] = pk_add(acc2[5], pk_mul(ee, (float2v){w2.z, w2.w}));
                        acc12 = acc12 + e * wl;
                    }
                }
            }
#pragma unroll
            for (int g = 0; g < 8; g++) eA[g] = eB[g];
        }
    } else {
        const float4* ep = (const float4*)((const float*)embv + (size_t)row * Hn);
        for (int c = 0; c < 12; c++) {
            float4 cur[16];
#pragma unroll
            for (int g = 0; g < 16; g++) cur[g] = ep[c * 16 + g];
            {
#pragma clang fp contract(off)
#pragma unroll
                for (int g = 0; g < 16; g++) {
#pragma unroll
                    for (int u = 0; u < 4; u++) {
                        int hg = c * 64 + g * 4 + u;
                        float e = (u == 0) ? cur[g].x : (u == 1) ? cur[g].y
                                : (u == 2) ? cur[g].z : cur[g].w;
                        float2v ee = (float2v){e, e};
                        const float4* wp4 = (const float4*)&wall[hg * 28 + j0];
                        float4 w0 = wp4[0];
                        float4 w1 = wp4[1];
                        float4 w2 = wp4[2];
                        float  wl = wall[hg * 28 + j0 + 12];
                        acc2[0] = pk_add(acc2[0], pk_mul(ee, (float2v){w0.x, w0.y}));
                        acc2[1] = pk_add(acc2[1], pk_mul(ee, (float2v){w0.z, w0.w}));
                        acc2[2] = pk_add(acc2[2], pk_mul(ee, (float2v){w1.x, w1.y}));
                        acc2[3] = pk_add(acc2[3], pk_mul(ee, (float2v){w1.z, w1.w}));
                        acc2[4] = pk_add(acc2[4], pk_mul(ee, (float2v){w2.x, w2.y}));
                        acc2[5] = pk_add(acc2[5], pk_mul(ee, (float2v){w2.z, w2.w}));
                        acc12 = acc12 + e * wl;
                    }
                }
            }
        }
    }

    // logits = einsum + b  (one f32 add, ref association); halves write disjoint j
    {
#pragma clang fp contract(off)
#pragma unroll
        for (int p = 0; p < 6; p++) {
            int j = j0 + 2 * p;
            logitsF[(size_t)row * 25 + j]     = acc2[p][0] + s_b[j];
            logitsF[(size_t)row * 25 + j + 1] = acc2[p][1] + s_b[j + 1];
        }
        if (half) logitsF[(size_t)row * 25 + 24] = acc12 + s_b[24];
    }
}

// ---------------- tail: viterbi (blocks 0..63) + lp (blocks 64..2111), fused ------
struct SharedV {
    float   lgl[Tn * Nn];    // 51200 B
    float   alpha[Tn][26];   // 53248 B
    uint8_t bp[511][32];     // 16352 B
    uint8_t tags[512];
};
struct SharedL {
    float s_trans[625];
    float s_start[25];
    float s_end[25];
};

__global__ __launch_bounds__(512) void k_tail(
    const float* logitsF, const float* wstrans, const float* wstc,
    const float* wsstart, const float* wsend, const float* wsscm, const float* wsecm,
    const int* lengths, const int* flags, void* out)
{
    __shared__ union { SharedV v; SharedL l; } smem;
    int tid = threadIdx.x;
    bool isbf = flags[0] != 0;

    if (blockIdx.x >= 64) {
        // ---------------- lp expansion ----------------
        for (int i = tid; i < 625; i += 512) smem.l.s_trans[i] = wstrans[i];
        if (tid < 25) { smem.l.s_start[tid] = wsstart[tid]; smem.l.s_end[tid] = wsend[tid]; }
        __syncthreads();

        int rw0 = (blockIdx.x - 64) * 16;    // 16 (b,t) rows, same batch
        int b = rw0 >> 9;
        int last = lengths[b] - 1;
        const float* lg0 = logitsF + (size_t)rw0 * 25;
        size_t obase = (size_t)rw0 * 625;

        for (int idx = tid; idx < 16 * 625; idx += 512) {
            int rr = idx / 625;
            int e  = idx - rr * 625;
            int j  = e % 25;
            int t  = (rw0 + rr) & 511;
            float lg = lg0[rr * 25 + j];
            float v;
            {
#pragma clang fp contract(off)
                if (t == 0) v = smem.l.s_start[j] + lg;
                else        v = lg + smem.l.s_trans[e];
                if (t == last) v += smem.l.s_end[j];
            }
            size_t o = obase + idx;
            if (isbf) ((__hip_bfloat16*)out)[o] = __float2bfloat16(v);
            else      ((float*)out)[o] = v;
        }
        return;
    }

    // ---------------- viterbi ----------------
    int b  = blockIdx.x;
    int len  = lengths[b];
    int last = len - 1;
    int padv = flags[2];
    int L   = tid & 63;
    int wid = tid >> 6;
    bool act = (L < 25);
    int j = act ? L : 0;

    // stage this batch's logits into LDS (coalesced float4, all 8 waves)
    {
        const float4* src = (const float4*)(logitsF + (size_t)b * (Tn * Nn));
        float4* dst = (float4*)smem.v.lgl;
        for (int i = tid; i < (Tn * Nn) / 4; i += 512) dst[i] = src[i];
    }

    // loop-invariant per-lane column: ttc only (trans+tc pre-add; exact when tc==0,
    // the only candidates that can win a followed argmax — tc|eye guarantees the
    // self-loop so NINF-class candidates lose by >=9e4). The t==last branches
    // reload trans/tc from global (identical values, cold path).
    float ttc[25];
#pragma unroll
    for (int k = 0; k < 25; k++) {
        ttc[k] = wstrans[k * 25 + j] + wstc[k * 25 + j];
    }
    float endj = wsend[j];
    float ecmj = wsecm[j];

    __syncthreads();   // lgl ready

    float areg = 0.0f;   // final alpha (valid in wave 0 lanes 0..24 after phase A)
    if (wid == 0) {
        // ---- phase A: max-only forward, 8-step unrolled, batched LDS ----
        {
#pragma clang fp contract(off)
            areg = (wsstart[j] + smem.v.lgl[j]) + wsscm[j];
        }
        if (act) smem.v.alpha[0][L] = areg;

        int tEndX = last - 1;            // inclusive end of steady-state steps
        int t = 1;
        for (; t + 7 <= tEndX; t += 8) {
            float Lg8[8];
#pragma unroll
            for (int u = 0; u < 8; u++) Lg8[u] = smem.v.lgl[(t + u) * 25 + j];
            float a8[8];
#pragma unroll
            for (int u = 0; u < 8; u++) { areg = stepx(areg, Lg8[u], ttc); a8[u] = areg; }
            if (act) {
#pragma unroll
                for (int u = 0; u < 8; u++) smem.v.alpha[t + u][L] = a8[u];
            }
        }
        for (; t <= tEndX; ++t) {
            float Lg = smem.v.lgl[t * 25 + j];
            areg = stepx(areg, Lg, ttc);
            if (act) smem.v.alpha[t][L] = areg;
        }
        // final step t = last (end-transition formula, exact ordering; reloads)
        {
            float Lg = smem.v.lgl[last * 25 + j];
            float s[25];
            {
#pragma clang fp contract(off)
#pragma unroll
                for (int k = 0; k < 25; k++) {
                    float tr = wstrans[k * 25 + j];
                    float tv = wstc[k * 25 + j];
                    float ak = rdlane(areg, k);
                    float v = (((Lg + tr) + endj) + tv) + ecmj;
                    s[k] = ak + v;
                }
            }
            areg = amax25(s);
            if (act) smem.v.alpha[last][L] = areg;
        }
    }
    __syncthreads();   // alpha rows ready

    // ---- phase B: bp[t][j], 8-way parallel over t ----
    for (int t = 1 + wid; t <= last; t += 8) {
        float ap = smem.v.alpha[t - 1][j];   // lane L holds alpha[t-1][L]
        float mj = smem.v.alpha[t][j];       // this j's row max
        float Lg = smem.v.lgl[t * 25 + j];

        float s[25];
        if (t < last) {
#pragma clang fp contract(off)
#pragma unroll
            for (int k = 0; k < 25; k++) {
                float ak = rdlane(ap, k);
                s[k] = ak + (Lg + ttc[k]);
            }
        } else {
#pragma clang fp contract(off)
#pragma unroll
            for (int k = 0; k < 25; k++) {
                float tr = wstrans[k * 25 + j];
                float tv = wstc[k * 25 + j];
                float ak = rdlane(ap, k);
                float v = (((Lg + tr) + endj) + tv) + ecmj;
                s[k] = ak + v;
            }
        }

        // first index with s[k]==mj  (== jnp.argmax first-occurrence; s recomputed
        // bit-identically to phase A, and the fmax-tree max is exact)
        int ik[25];
#pragma unroll
        for (int k = 0; k < 25; k++) ik[k] = (s[k] == mj) ? k : 32;
        int q0 = imin2(imin2(ik[0],  ik[1]),  ik[2]);
        int q1 = imin2(imin2(ik[3],  ik[4]),  ik[5]);
        int q2 = imin2(imin2(ik[6],  ik[7]),  ik[8]);
        int q3 = imin2(imin2(ik[9],  ik[10]), ik[11]);
        int q4 = imin2(imin2(ik[12], ik[13]), ik[14]);
        int q5 = imin2(imin2(ik[15], ik[16]), ik[17]);
        int q6 = imin2(imin2(ik[18], ik[19]), ik[20]);
        int q7 = imin2(imin2(ik[21], ik[22]), ik[23]);
        int r0 = imin2(imin2(q0, q1), q2);
        int r1 = imin2(imin2(q3, q4), q5);
        int r2 = imin2(imin2(q6, q7), ik[24]);
        int mi = imin2(imin2(r0, r1), r2);

        if (act) smem.v.bp[t - 1][L] = (uint8_t)mi;
    }
    __syncthreads();   // bp ready

    if (wid == 0) {
        // wave-uniform argmax over final alpha (readlane chain, first-max)
        float am = rdlane(areg, 0);
        int ami = 0;
#pragma unroll
        for (int k = 1; k < 25; k++) {
            float v2 = rdlane(areg, k);
            bool g = v2 > am;
            am  = g ? v2 : am;
            ami = g ? k  : ami;
        }
        int tag = ami;
        if (L == 0) smem.v.tags[last] = (uint8_t)tag;

        // backtrack: prefetch 8 bp rows per chunk (independent LDS reads), then
        // chain only through dynamic-lane readlane.
        int Lc = L & 31;
        int k2 = last - 1;
        while (k2 >= 7) {
            int c0 = smem.v.bp[k2    ][Lc];
            int c1 = smem.v.bp[k2 - 1][Lc];
            int c2 = smem.v.bp[k2 - 2][Lc];
            int c3 = smem.v.bp[k2 - 3][Lc];
            int c4 = smem.v.bp[k2 - 4][Lc];
            int c5 = smem.v.bp[k2 - 5][Lc];
            int c6 = smem.v.bp[k2 - 6][Lc];
            int c7 = smem.v.bp[k2 - 7][Lc];
            tag = __builtin_amdgcn_readlane(c0, tag); if (L == 0) smem.v.tags[k2    ] = (uint8_t)tag;
            tag = __builtin_amdgcn_readlane(c1, tag); if (L == 0) smem.v.tags[k2 - 1] = (uint8_t)tag;
            tag = __builtin_amdgcn_readlane(c2, tag); if (L == 0) smem.v.tags[k2 - 2] = (uint8_t)tag;
            tag = __builtin_amdgcn_readlane(c3, tag); if (L == 0) smem.v.tags[k2 - 3] = (uint8_t)tag;
            tag = __builtin_amdgcn_readlane(c4, tag); if (L == 0) smem.v.tags[k2 - 4] = (uint8_t)tag;
            tag = __builtin_amdgcn_readlane(c5, tag); if (L == 0) smem.v.tags[k2 - 5] = (uint8_t)tag;
            tag = __builtin_amdgcn_readlane(c6, tag); if (L == 0) smem.v.tags[k2 - 6] = (uint8_t)tag;
            tag = __builtin_amdgcn_readlane(c7, tag); if (L == 0) smem.v.tags[k2 - 7] = (uint8_t)tag;
            k2 -= 8;
        }
        while (k2 >= 0) {
            int c = smem.v.bp[k2][Lc];
            tag = __builtin_amdgcn_readlane(c, tag);
            if (L == 0) smem.v.tags[k2] = (uint8_t)tag;
            k2--;
        }
    }
    __syncthreads();

    size_t base = 20480000ull;  // B*T*N*N
    {
        int t = tid;            // 512 threads, one element each
        float val = (t < len) ? (float)smem.v.tags[t] : (float)padv;
        size_t o = base + (size_t)b * 512 + t;
        if (isbf) ((__hip_bfloat16*)out)[o] = __float2bfloat16(val);
        else      ((float*)out)[o] = val;
    }
}

extern "C" void kernel_launch(void* const* d_in, const int* in_sizes, int n_in,
                              void* d_out, int out_size, void* d_ws, size_t ws_size,
                              hipStream_t stream) {
    const void* emb  = d_in[0];
    const void* W    = d_in[1];
    const void* bv   = d_in[2];
    const void* tr   = d_in[3];
    const void* st   = d_in[4];
    const void* en   = d_in[5];
    const void* mask = d_in[6];
    const void* sc   = d_in[7];
    const void* ec   = d_in[8];
    const void* tc   = d_in[9];
    const void* pad  = d_in[10];

    char* ws = (char*)d_ws;
    int*    flags    = (int*)ws;             // 64 B
    int*    lengths  = (int*)(ws + 64);      // 256 B
    float*  wsstart  = (float*)(ws + 512);
    float*  wsend    = (float*)(ws + 640);
    float*  wsscm    = (float*)(ws + 768);
    float*  wsecm    = (float*)(ws + 896);
    float*  wstrans  = (float*)(ws + 1024);  // 2500 B
    float*  wstc     = (float*)(ws + 3584);  // 2500 B
    float*  logitsF  = (float*)(ws + 82944); // 3276800 B -> ends ~3.36 MB

    k_prep<<<64, 256, 0, stream>>>(emb, mask, pad, tr, st, en, sc, ec, tc,
                                   flags, wsstart, wsend, wsscm, wsecm,
                                   wstrans, wstc, lengths);
    k_gemm<<<256, 256, 0, stream>>>(emb, W, bv, logitsF);
    k_tail<<<2112, 512, 0, stream>>>(logitsF, wstrans, wstc, wsstart, wsend,
                                     wsscm, wsecm, lengths, flags, d_out);
}